// Round 8
// baseline (14870.488 us; speedup 1.0000x reference)
//
#include <hip/hip_runtime.h>
#include <stdint.h>

// LSTM: T=1024, B=32, I=512, H=512, fp32. Persistent-style, plain launch.
// R12 (post-mortem R11: WRITE_SIZE 0.2->17.8GB = scratch spill of v[16]
// under divergent if(cons) -- rule: ring arrays <=8 words, uniform exec.
// REVERTED to exact R7 champion (3742us) + ONE delta):
//  - barrier D (t>0) replaced by 4 chunked LDS flags. htile h-columns
//    [128j,128j+128) are written exactly by waves 2j,2j+1; h-proj's j-loop
//    reads exactly chunk j. Writer wave release-adds hflag[j] after its
//    htile stores; readers acquire-spin hflag[j] >= 2t before chunk j.
//    Late producers' chunks overlap with FMA on ready chunks instead of
//    convoying all 8 waves at D. Deadlock-free: phase 4 has no
//    block-internal waits; E/F/A still order all cross-step LDS reuse
//    (htile write(t+1) vs read(t) separated by E(t),F(t),A(t+1)).
//  - t==0 keeps a plain barrier (h0 staged by all threads).
// Session rules: knee=2 waves/SIMD; ring first-look post-A only; publish
// from single wave; garr/F harmless; no divergent big arrays.
// Ring protocol unchanged from R4: fused ((fp32_bits<<32)|tag) words, depth 4,
// relaxed agent-scope atomics, poison 0xAAAAAAAA != any tag (1..1024).
//
// 256 blocks = 4 batch-groups (bg) x 64 j-groups (jg). Weights in VGPRs for
// all 1024 steps. c-state block-local. out[] gets plain fp32 stores only.

#define T_STEPS 1024
#define BATCH   32
#define IDIM    512
#define HDIM    512

#define BG      4
#define JG      64
#define NBLK    (BG*JG)
#define BPB     (BATCH/BG)   // 8 batches/block
#define JPB     (HDIM/JG)    // 8 hidden units/block
#define RPB     (4*JPB)      // 32 gate rows/block
#define NTHR    512          // 8 waves -> 2 waves/SIMD (R7-proven knee)
#define PSTRIDE 257          // odd stride -> worst 2-way (free) LDS conflicts
#define RING_D  4
#define HWORDS  (BPB*HDIM)   // 4096 tagged words per (slot,bg)
#define WPT     (HWORDS/NTHR) // 8 words per consumer thread (uniform exec)

__device__ __forceinline__ float sigmoid_f(float v) {
    return 1.0f / (1.0f + __expf(-v));
}
__device__ __forceinline__ float tanh_f(float v) {
    float e = __expf(2.0f * v);
    return 1.0f - 2.0f / (e + 1.0f);
}

__global__ __launch_bounds__(NTHR, 1) void lstm_persistent(
    const float* __restrict__ x,     // [T][B][I]
    const float* __restrict__ h0,    // [B][H]
    const float* __restrict__ c0,    // [B][H]
    const float* __restrict__ Wih,   // [4H][I]
    const float* __restrict__ Whh,   // [4H][H]
    const float* __restrict__ bih,   // [4H]
    const float* __restrict__ bhh,   // [4H]
    float* __restrict__ out,         // [T][B][H] ++ h_f[B][H] ++ c_f[B][H]
    unsigned long long* __restrict__ ring)  // [4][BG][HWORDS] tagged words
{
    __shared__ __align__(16) float xtile[BPB * IDIM];   // 16 KB
    __shared__ __align__(16) float htile[BPB * HDIM];   // 16 KB
    __shared__ float part[RPB * PSTRIDE];               // 32.9 KB
    __shared__ float garr[RPB * 9];
    __shared__ float biasl[RPB];
    __shared__ int   hflag[4];       // monotone chunk counters (2 per step)

    const int tid = threadIdx.x;
    const int bid = blockIdx.x;
    const int bg  = bid >> 6;        // 0..3
    const int jg  = bid & 63;        // 0..63
    const int ks  = tid >> 4;        // 0..31 k-slice
    const int rp  = tid & 15;        // 0..15 row-pair

    // ---- weight slices -> registers (held for all steps) ----
    float4 wih[2][4], whh[2][4];
    #pragma unroll
    for (int r = 0; r < 2; ++r) {
        const int lr = rp * 2 + r;                                // 0..31
        const int grow = (lr >> 3) * HDIM + jg * JPB + (lr & 7);  // gate*512+j
        const float* wi = Wih + (size_t)grow * IDIM;
        const float* wh = Whh + (size_t)grow * HDIM;
        #pragma unroll
        for (int j = 0; j < 4; ++j) {
            const int k = ks * 4 + j * 128;
            wih[r][j] = *(const float4*)(wi + k);
            whh[r][j] = *(const float4*)(wh + k);
        }
    }
    if (tid < RPB) {
        const int grow = (tid >> 3) * HDIM + jg * JPB + (tid & 7);
        biasl[tid] = bih[grow] + bhh[grow];
    }
    if (tid < 4) hflag[tid] = 0;

    // activation threads: 64 threads (wave 0) x 1 cell each
    const int ab = tid >> 3;          // batch 0..7 (tid<64)
    const int j1 = tid & 7;           // j within block slice
    float cst = 0.f, hl = 0.f;
    if (tid < 64) {
        cst = c0[(size_t)(bg * BPB + ab) * HDIM + jg * JPB + j1];
    }
    __syncthreads();

    for (int t = 0; t < T_STEPS; ++t) {
        // ---- 1. stage x[t] (contiguous lane mapping, conflict-free) ----
        {
            const float* xsrc = x + ((size_t)t * BATCH + bg * BPB) * IDIM;
            #pragma unroll
            for (int i = 0; i < 2; ++i) {
                const int f = i * 2048 + tid * 4;
                *(float4*)(xtile + f) = *(const float4*)(xsrc + f);
            }
        }
        __syncthreads();   // A: xtile ready; also orders part/htile reuse

        // ---- 2. prefetch tagged h(t-1) words (RT hides under x-proj) ----
        // R7-proven timing: AFTER x-stage + barrier A. Do not move earlier.
        unsigned long long v[WPT];
        const unsigned int tag = (unsigned int)t;   // producers wrote (t-1)+1
        const unsigned long long* rb =
            ring + ((size_t)((t - 1) & 3) * BG + bg) * HWORDS;
        if (t > 0) {
            #pragma unroll
            for (int w = 0; w < WPT; ++w)
                v[w] = __hip_atomic_load(rb + w * NTHR + tid,
                                         __ATOMIC_RELAXED,
                                         __HIP_MEMORY_SCOPE_AGENT);
        }

        // ---- 3. x projection ----
        float acc[2][BPB];
        #pragma unroll
        for (int r = 0; r < 2; ++r)
            #pragma unroll
            for (int b = 0; b < BPB; ++b) acc[r][b] = 0.0f;

        #pragma unroll
        for (int j = 0; j < 4; ++j) {
            #pragma unroll
            for (int b = 0; b < BPB; ++b) {
                const float4 vx = *(const float4*)(xtile + b * IDIM + ks * 4 + j * 128);
                #pragma unroll
                for (int r = 0; r < 2; ++r) {
                    acc[r][b] = fmaf(wih[r][j].x, vx.x, acc[r][b]);
                    acc[r][b] = fmaf(wih[r][j].y, vx.y, acc[r][b]);
                    acc[r][b] = fmaf(wih[r][j].z, vx.z, acc[r][b]);
                    acc[r][b] = fmaf(wih[r][j].w, vx.w, acc[r][b]);
                }
            }
        }

        // ---- 4. validate tags; reload stragglers; htile write + flag ----
        if (t > 0) {
            for (int sweep = 0; sweep < 30000; ++sweep) {
                bool ok = true;
                #pragma unroll
                for (int w = 0; w < WPT; ++w) {
                    if ((unsigned int)v[w] != tag) {
                        v[w] = __hip_atomic_load(rb + w * NTHR + tid,
                                                 __ATOMIC_RELAXED,
                                                 __HIP_MEMORY_SCOPE_AGENT);
                        ok = false;
                    }
                }
                if (ok) break;                     // bail path -> visible error
                __builtin_amdgcn_s_sleep(1);
            }
            #pragma unroll
            for (int w = 0; w < WPT; ++w)
                htile[w * NTHR + tid] =
                    __uint_as_float((unsigned int)(v[w] >> 32));
            // wave (tid>>6) wrote h-columns [64w,64w+64) => chunk tid>>7.
            // release-add: orders the ds_writes above before the flag.
            if ((tid & 63) == 0)
                __hip_atomic_fetch_add(&hflag[tid >> 7], 1,
                                       __ATOMIC_RELEASE,
                                       __HIP_MEMORY_SCOPE_WORKGROUP);
        } else {
            const float* hsrc = h0 + (size_t)bg * BPB * HDIM;
            #pragma unroll
            for (int i = 0; i < 2; ++i) {
                const int f = i * 2048 + tid * 4;
                *(float4*)(htile + f) = *(const float4*)(hsrc + f);
            }
        }
        if (t == 0) __syncthreads();   // D only at t=0 (h0 staged by all)

        // ---- 5. h projection; chunk j gated by hflag[j] >= 2t ----
        #pragma unroll
        for (int j = 0; j < 4; ++j) {
            if (t > 0) {
                const int target = 2 * t;
                int spin = 0;
                while (__hip_atomic_load(&hflag[j], __ATOMIC_ACQUIRE,
                                         __HIP_MEMORY_SCOPE_WORKGROUP)
                       < target) {
                    if (++spin > 2000000) break;   // bail -> visible error
                }
            }
            #pragma unroll
            for (int b = 0; b < BPB; ++b) {
                const float4 vh = *(const float4*)(htile + b * HDIM + ks * 4 + j * 128);
                #pragma unroll
                for (int r = 0; r < 2; ++r) {
                    acc[r][b] = fmaf(whh[r][j].x, vh.x, acc[r][b]);
                    acc[r][b] = fmaf(whh[r][j].y, vh.y, acc[r][b]);
                    acc[r][b] = fmaf(whh[r][j].z, vh.z, acc[r][b]);
                    acc[r][b] = fmaf(whh[r][j].w, vh.w, acc[r][b]);
                }
            }
        }

        // ---- 6. spill partials ----
        #pragma unroll
        for (int r = 0; r < 2; ++r) {
            const int lr = rp * 2 + r;
            #pragma unroll
            for (int b = 0; b < BPB; ++b)
                part[lr * PSTRIDE + b * 32 + ks] = acc[r][b];
        }
        __syncthreads();   // E

        // ---- 7. reduce 32 k-slices (first 256 threads) ----
        if (tid < 256) {
            const int b  = tid >> 5;
            const int lr = tid & 31;
            const float* p = part + lr * PSTRIDE + b * 32;
            float s0 = 0.f, s1 = 0.f, s2 = 0.f, s3 = 0.f;
            #pragma unroll
            for (int k2 = 0; k2 < 32; k2 += 4) {
                s0 += p[k2]; s1 += p[k2 + 1]; s2 += p[k2 + 2]; s3 += p[k2 + 3];
            }
            garr[lr * 9 + b] = (s0 + s1) + (s2 + s3) + biasl[lr];
        }
        __syncthreads();   // F

        // ---- 8. activations, state update, publish (wave 0, 1 cell) ----
        if (tid < 64) {
            const float ig = sigmoid_f(garr[(0 * 8 + j1) * 9 + ab]);
            const float fg = sigmoid_f(garr[(1 * 8 + j1) * 9 + ab]);
            const float gg = tanh_f  (garr[(2 * 8 + j1) * 9 + ab]);
            const float og = sigmoid_f(garr[(3 * 8 + j1) * 9 + ab]);
            cst = fmaf(fg, cst, ig * gg);
            hl  = og * tanh_f(cst);

            // tagged ring publish FIRST (earliest visibility on chain)
            unsigned long long* rw = ring
                + ((size_t)(t & 3) * BG + bg) * HWORDS
                + ab * HDIM + jg * JPB + j1;
            __hip_atomic_store(rw,
                (((unsigned long long)__float_as_uint(hl)) << 32)
                    | (unsigned long long)(t + 1),
                __ATOMIC_RELAXED, __HIP_MEMORY_SCOPE_AGENT);

            // output store (plain; nobody reads out[] during the run)
            out[((size_t)t * BATCH + bg * BPB + ab) * HDIM + jg * JPB + j1] = hl;
        }
        // no barrier here: A/E/F + chunk flags separate all hazards
    }

    // ---- final states h_f, c_f ----
    if (tid < 64) {
        const size_t base = (size_t)T_STEPS * BATCH * HDIM;
        const size_t off  = (size_t)(bg * BPB + ab) * HDIM + jg * JPB + j1;
        out[base + off] = hl;
        out[base + (size_t)BATCH * HDIM + off] = cst;
    }
}

extern "C" void kernel_launch(void* const* d_in, const int* in_sizes, int n_in,
                              void* d_out, int out_size, void* d_ws, size_t ws_size,
                              hipStream_t stream) {
    const float* x   = (const float*)d_in[0];
    const float* h0  = (const float*)d_in[1];
    const float* c0  = (const float*)d_in[2];
    const float* Wih = (const float*)d_in[3];
    const float* Whh = (const float*)d_in[4];
    const float* bih = (const float*)d_in[5];
    const float* bhh = (const float*)d_in[6];
    float* out = (float*)d_out;
    unsigned long long* ring = (unsigned long long*)d_ws;  // 512 KB; 0xAA poison
                                                           // != any tag -> no init
    lstm_persistent<<<dim3(NBLK), dim3(NTHR), 0, stream>>>(
        x, h0, c0, Wih, Whh, bih, bhh, out, ring);
}

// Round 9
// 3736.850 us; speedup vs baseline: 3.9794x; 3.9794x over previous
//
#include <hip/hip_runtime.h>
#include <stdint.h>

// LSTM: T=1024, B=32, I=512, H=512, fp32. Persistent-style, plain launch.
// R13 = R7 champion (3742 us) byte-identical EXCEPT ring atomic scope
// AGENT -> SYSTEM (sc0+sc1: bypass L1/L2, read/write the coherence point).
// Theory: R7's missing ~5000 cyc/step is consumers polling STALE local-XCD
// L2 lines (per-XCD L2s are not cross-invalidated); sweep duration was
// governed by L2 eviction, not the ~700cy L3 RT. Evidence: first-look
// traffic alone is ~8.4 GB/run but champion FETCH was 0.79 GB -> ring
// loads were served by local L2. System scope forces coherent reads.
// Discriminating prediction: if right, FETCH explodes to 6-10 GB and dur
// drops to ~2.8-3.3 ms; if loads already bypassed, no change; if the
// coherent path is slower, small regression -> revert.
// (R8-R12 post-mortems: occupancy knee = 2 waves/SIMD; ring first-look
// post-A only; publish from single wave; no divergent/big ring arrays;
// no spin-waits inside the FMA loops.)
//
// 256 blocks = 4 batch-groups (bg) x 64 j-groups (jg). Weights in VGPRs for
// all 1024 steps. c-state block-local. out[] gets plain fp32 stores only.

#define T_STEPS 1024
#define BATCH   32
#define IDIM    512
#define HDIM    512

#define BG      4
#define JG      64
#define NBLK    (BG*JG)
#define BPB     (BATCH/BG)   // 8 batches/block
#define JPB     (HDIM/JG)    // 8 hidden units/block
#define RPB     (4*JPB)      // 32 gate rows/block
#define NTHR    512          // 8 waves -> 2 waves/SIMD (R7-proven knee)
#define PSTRIDE 257          // odd stride -> worst 2-way (free) LDS conflicts
#define RING_D  4
#define HWORDS  (BPB*HDIM)   // 4096 tagged words per (slot,bg)
#define WPT     (HWORDS/NTHR) // 8 words per consumer thread

__device__ __forceinline__ float sigmoid_f(float v) {
    return 1.0f / (1.0f + __expf(-v));
}
__device__ __forceinline__ float tanh_f(float v) {
    float e = __expf(2.0f * v);
    return 1.0f - 2.0f / (e + 1.0f);
}

__global__ __launch_bounds__(NTHR, 1) void lstm_persistent(
    const float* __restrict__ x,     // [T][B][I]
    const float* __restrict__ h0,    // [B][H]
    const float* __restrict__ c0,    // [B][H]
    const float* __restrict__ Wih,   // [4H][I]
    const float* __restrict__ Whh,   // [4H][H]
    const float* __restrict__ bih,   // [4H]
    const float* __restrict__ bhh,   // [4H]
    float* __restrict__ out,         // [T][B][H] ++ h_f[B][H] ++ c_f[B][H]
    unsigned long long* __restrict__ ring)  // [4][BG][HWORDS] tagged words
{
    __shared__ __align__(16) float xtile[BPB * IDIM];   // 16 KB
    __shared__ __align__(16) float htile[BPB * HDIM];   // 16 KB
    __shared__ float part[RPB * PSTRIDE];               // 32.9 KB
    __shared__ float garr[RPB * 9];
    __shared__ float biasl[RPB];

    const int tid = threadIdx.x;
    const int bid = blockIdx.x;
    const int bg  = bid >> 6;        // 0..3
    const int jg  = bid & 63;        // 0..63
    const int ks  = tid >> 4;        // 0..31 k-slice
    const int rp  = tid & 15;        // 0..15 row-pair

    // ---- weight slices -> registers (held for all steps) ----
    float4 wih[2][4], whh[2][4];
    #pragma unroll
    for (int r = 0; r < 2; ++r) {
        const int lr = rp * 2 + r;                                // 0..31
        const int grow = (lr >> 3) * HDIM + jg * JPB + (lr & 7);  // gate*512+j
        const float* wi = Wih + (size_t)grow * IDIM;
        const float* wh = Whh + (size_t)grow * HDIM;
        #pragma unroll
        for (int j = 0; j < 4; ++j) {
            const int k = ks * 4 + j * 128;
            wih[r][j] = *(const float4*)(wi + k);
            whh[r][j] = *(const float4*)(wh + k);
        }
    }
    if (tid < RPB) {
        const int grow = (tid >> 3) * HDIM + jg * JPB + (tid & 7);
        biasl[tid] = bih[grow] + bhh[grow];
    }

    // activation threads: 64 threads (wave 0) x 1 cell each
    const int ab = tid >> 3;          // batch 0..7 (tid<64)
    const int j1 = tid & 7;           // j within block slice
    float cst = 0.f, hl = 0.f;
    if (tid < 64) {
        cst = c0[(size_t)(bg * BPB + ab) * HDIM + jg * JPB + j1];
    }
    __syncthreads();

    for (int t = 0; t < T_STEPS; ++t) {
        // ---- 1. stage x[t] (contiguous lane mapping, conflict-free) ----
        {
            const float* xsrc = x + ((size_t)t * BATCH + bg * BPB) * IDIM;
            #pragma unroll
            for (int i = 0; i < 2; ++i) {
                const int f = i * 2048 + tid * 4;
                *(float4*)(xtile + f) = *(const float4*)(xsrc + f);
            }
        }
        __syncthreads();   // A: xtile ready; also orders garr/part reuse

        // ---- 2. prefetch tagged h(t-1) words (RT hides under x-proj) ----
        // R7-proven timing: AFTER x-stage + barrier A. Do not move earlier.
        unsigned long long v[WPT];
        const unsigned int tag = (unsigned int)t;   // producers wrote (t-1)+1
        const unsigned long long* rb =
            ring + ((size_t)((t - 1) & 3) * BG + bg) * HWORDS;
        if (t > 0) {
            #pragma unroll
            for (int w = 0; w < WPT; ++w)
                v[w] = __hip_atomic_load(rb + w * NTHR + tid,
                                         __ATOMIC_RELAXED,
                                         __HIP_MEMORY_SCOPE_SYSTEM);
        }

        // ---- 3. x projection ----
        float acc[2][BPB];
        #pragma unroll
        for (int r = 0; r < 2; ++r)
            #pragma unroll
            for (int b = 0; b < BPB; ++b) acc[r][b] = 0.0f;

        #pragma unroll
        for (int j = 0; j < 4; ++j) {
            #pragma unroll
            for (int b = 0; b < BPB; ++b) {
                const float4 vx = *(const float4*)(xtile + b * IDIM + ks * 4 + j * 128);
                #pragma unroll
                for (int r = 0; r < 2; ++r) {
                    acc[r][b] = fmaf(wih[r][j].x, vx.x, acc[r][b]);
                    acc[r][b] = fmaf(wih[r][j].y, vx.y, acc[r][b]);
                    acc[r][b] = fmaf(wih[r][j].z, vx.z, acc[r][b]);
                    acc[r][b] = fmaf(wih[r][j].w, vx.w, acc[r][b]);
                }
            }
        }

        // ---- 4. validate tags; reload stragglers; write h into htile ----
        if (t > 0) {
            for (int sweep = 0; sweep < 30000; ++sweep) {
                bool ok = true;
                #pragma unroll
                for (int w = 0; w < WPT; ++w) {
                    if ((unsigned int)v[w] != tag) {
                        v[w] = __hip_atomic_load(rb + w * NTHR + tid,
                                                 __ATOMIC_RELAXED,
                                                 __HIP_MEMORY_SCOPE_SYSTEM);
                        ok = false;
                    }
                }
                if (ok) break;                     // bail path -> visible error
                __builtin_amdgcn_s_sleep(1);
            }
            #pragma unroll
            for (int w = 0; w < WPT; ++w)
                htile[w * NTHR + tid] =
                    __uint_as_float((unsigned int)(v[w] >> 32));
        } else {
            const float* hsrc = h0 + (size_t)bg * BPB * HDIM;
            #pragma unroll
            for (int i = 0; i < 2; ++i) {
                const int f = i * 2048 + tid * 4;
                *(float4*)(htile + f) = *(const float4*)(hsrc + f);
            }
        }
        __syncthreads();   // D: htile ready

        // ---- 5. h projection ----
        #pragma unroll
        for (int j = 0; j < 4; ++j) {
            #pragma unroll
            for (int b = 0; b < BPB; ++b) {
                const float4 vh = *(const float4*)(htile + b * HDIM + ks * 4 + j * 128);
                #pragma unroll
                for (int r = 0; r < 2; ++r) {
                    acc[r][b] = fmaf(whh[r][j].x, vh.x, acc[r][b]);
                    acc[r][b] = fmaf(whh[r][j].y, vh.y, acc[r][b]);
                    acc[r][b] = fmaf(whh[r][j].z, vh.z, acc[r][b]);
                    acc[r][b] = fmaf(whh[r][j].w, vh.w, acc[r][b]);
                }
            }
        }

        // ---- 6. spill partials ----
        #pragma unroll
        for (int r = 0; r < 2; ++r) {
            const int lr = rp * 2 + r;
            #pragma unroll
            for (int b = 0; b < BPB; ++b)
                part[lr * PSTRIDE + b * 32 + ks] = acc[r][b];
        }
        __syncthreads();   // E

        // ---- 7. reduce 32 k-slices (first 256 threads) ----
        if (tid < 256) {
            const int b  = tid >> 5;
            const int lr = tid & 31;
            const float* p = part + lr * PSTRIDE + b * 32;
            float s0 = 0.f, s1 = 0.f, s2 = 0.f, s3 = 0.f;
            #pragma unroll
            for (int k2 = 0; k2 < 32; k2 += 4) {
                s0 += p[k2]; s1 += p[k2 + 1]; s2 += p[k2 + 2]; s3 += p[k2 + 3];
            }
            garr[lr * 9 + b] = (s0 + s1) + (s2 + s3) + biasl[lr];
        }
        __syncthreads();   // F

        // ---- 8. activations, state update, publish (wave 0, 1 cell) ----
        if (tid < 64) {
            const float ig = sigmoid_f(garr[(0 * 8 + j1) * 9 + ab]);
            const float fg = sigmoid_f(garr[(1 * 8 + j1) * 9 + ab]);
            const float gg = tanh_f  (garr[(2 * 8 + j1) * 9 + ab]);
            const float og = sigmoid_f(garr[(3 * 8 + j1) * 9 + ab]);
            cst = fmaf(fg, cst, ig * gg);
            hl  = og * tanh_f(cst);

            // tagged ring publish FIRST (earliest visibility on chain)
            unsigned long long* rw = ring
                + ((size_t)(t & 3) * BG + bg) * HWORDS
                + ab * HDIM + jg * JPB + j1;
            __hip_atomic_store(rw,
                (((unsigned long long)__float_as_uint(hl)) << 32)
                    | (unsigned long long)(t + 1),
                __ATOMIC_RELAXED, __HIP_MEMORY_SCOPE_SYSTEM);

            // output store (plain; nobody reads out[] during the run)
            out[((size_t)t * BATCH + bg * BPB + ab) * HDIM + jg * JPB + j1] = hl;
        }
        // no barrier here: A/D/E/F already separate all cross-step hazards
    }

    // ---- final states h_f, c_f ----
    if (tid < 64) {
        const size_t base = (size_t)T_STEPS * BATCH * HDIM;
        const size_t off  = (size_t)(bg * BPB + ab) * HDIM + jg * JPB + j1;
        out[base + off] = hl;
        out[base + (size_t)BATCH * HDIM + off] = cst;
    }
}

extern "C" void kernel_launch(void* const* d_in, const int* in_sizes, int n_in,
                              void* d_out, int out_size, void* d_ws, size_t ws_size,
                              hipStream_t stream) {
    const float* x   = (const float*)d_in[0];
    const float* h0  = (const float*)d_in[1];
    const float* c0  = (const float*)d_in[2];
    const float* Wih = (const float*)d_in[3];
    const float* Whh = (const float*)d_in[4];
    const float* bih = (const float*)d_in[5];
    const float* bhh = (const float*)d_in[6];
    float* out = (float*)d_out;
    unsigned long long* ring = (unsigned long long*)d_ws;  // 512 KB; 0xAA poison
                                                           // != any tag -> no init
    lstm_persistent<<<dim3(NBLK), dim3(NTHR), 0, stream>>>(
        x, h0, c0, Wih, Whh, bih, bhh, out, ring);
}

// Round 10
// 3678.162 us; speedup vs baseline: 4.0429x; 1.0160x over previous
//
#include <hip/hip_runtime.h>
#include <stdint.h>

// LSTM: T=1024, B=32, I=512, H=512, fp32. Persistent-style, plain launch.
// R14 (post-mortem R13: scope AGENT->SYSTEM = NO change -> coherence was
// never the issue; ring protocol is fine. New audit: LDS read port.
// R7/R13 issue 64 ds_read_b128/thread/step (8 FMA per read) -> ~6100cy of
// LDS pipe occupancy per 8770cy step, sitting on the serial skeleton
// between barriers A-D and D-E.)
// R14 = R13 skeleton byte-identical EXCEPT thread remap:
//  - tid = ks(0..63)*8 + rq(0..7); 4 rows x 8 contiguous k per thread
//    (2 float4/matrix, same 64 weight VGPRs). FMA unchanged; b128 reads
//    HALVE to 32/thread (16 FMA/read). Broadcasts (8 rq-lanes share vx)
//    stay free.
//  - part[] 32 rows x (8b x 64ks), PSTRIDE 513 (spill 2-way, reduce
//    2-way -- both free). Reduce uses all 512 threads (half-column each)
//    into garr2[2][.]; activation sums the two halves -> tail wall-time
//    unchanged vs R7.
// Session rules: knee=2 waves/SIMD; ring first-look post-A only; publish
// from single wave; no divergent big arrays; no spins inside FMA loops.
// Ring protocol unchanged from R4: fused ((fp32_bits<<32)|tag) words, depth 4,
// relaxed system-scope atomics, poison 0xAAAAAAAA != any tag (1..1024).
//
// 256 blocks = 4 batch-groups (bg) x 64 j-groups (jg). Weights in VGPRs for
// all 1024 steps. c-state block-local. out[] gets plain fp32 stores only.

#define T_STEPS 1024
#define BATCH   32
#define IDIM    512
#define HDIM    512

#define BG      4
#define JG      64
#define NBLK    (BG*JG)
#define BPB     (BATCH/BG)   // 8 batches/block
#define JPB     (HDIM/JG)    // 8 hidden units/block
#define RPB     (4*JPB)      // 32 gate rows/block
#define NTHR    512          // 8 waves -> 2 waves/SIMD (proven knee)
#define PSTRIDE 513          // odd -> 2-way (free) spill/reduce conflicts
#define RING_D  4
#define HWORDS  (BPB*HDIM)   // 4096 tagged words per (slot,bg)
#define WPT     (HWORDS/NTHR) // 8 words per consumer thread

__device__ __forceinline__ float sigmoid_f(float v) {
    return 1.0f / (1.0f + __expf(-v));
}
__device__ __forceinline__ float tanh_f(float v) {
    float e = __expf(2.0f * v);
    return 1.0f - 2.0f / (e + 1.0f);
}

__global__ __launch_bounds__(NTHR, 1) void lstm_persistent(
    const float* __restrict__ x,     // [T][B][I]
    const float* __restrict__ h0,    // [B][H]
    const float* __restrict__ c0,    // [B][H]
    const float* __restrict__ Wih,   // [4H][I]
    const float* __restrict__ Whh,   // [4H][H]
    const float* __restrict__ bih,   // [4H]
    const float* __restrict__ bhh,   // [4H]
    float* __restrict__ out,         // [T][B][H] ++ h_f[B][H] ++ c_f[B][H]
    unsigned long long* __restrict__ ring)  // [4][BG][HWORDS] tagged words
{
    __shared__ __align__(16) float xtile[BPB * IDIM];   // 16 KB
    __shared__ __align__(16) float htile[BPB * HDIM];   // 16 KB
    __shared__ float part[RPB * PSTRIDE];               // 65.7 KB
    __shared__ float garr2[2 * RPB * 9];                // two half-sums
    __shared__ float biasl[RPB];

    const int tid = threadIdx.x;
    const int bid = blockIdx.x;
    const int bg  = bid >> 6;        // 0..3
    const int jg  = bid & 63;        // 0..63
    const int ks  = tid >> 3;        // 0..63 k-slice (8 contiguous floats)
    const int rq  = tid & 7;         // 0..7  row-quad

    // ---- weight slices -> registers (held for all steps) ----
    // each thread: 4 gate-rows x 8 contiguous k (2 float4) per matrix
    float4 wih[4][2], whh[4][2];
    #pragma unroll
    for (int r = 0; r < 4; ++r) {
        const int lr = rq * 4 + r;                                // 0..31
        const int grow = (lr >> 3) * HDIM + jg * JPB + (lr & 7);  // gate*512+j
        const float* wi = Wih + (size_t)grow * IDIM + ks * 8;
        const float* wh = Whh + (size_t)grow * HDIM + ks * 8;
        #pragma unroll
        for (int hf = 0; hf < 2; ++hf) {
            wih[r][hf] = *(const float4*)(wi + hf * 4);
            whh[r][hf] = *(const float4*)(wh + hf * 4);
        }
    }
    if (tid < RPB) {
        const int grow = (tid >> 3) * HDIM + jg * JPB + (tid & 7);
        biasl[tid] = bih[grow] + bhh[grow];
    }

    // activation threads: 64 threads (wave 0) x 1 cell each
    const int ab = tid >> 3;          // batch 0..7 (tid<64)
    const int j1 = tid & 7;           // j within block slice
    float cst = 0.f, hl = 0.f;
    if (tid < 64) {
        cst = c0[(size_t)(bg * BPB + ab) * HDIM + jg * JPB + j1];
    }
    __syncthreads();

    for (int t = 0; t < T_STEPS; ++t) {
        // ---- 1. stage x[t] (contiguous lane mapping, conflict-free) ----
        {
            const float* xsrc = x + ((size_t)t * BATCH + bg * BPB) * IDIM;
            #pragma unroll
            for (int i = 0; i < 2; ++i) {
                const int f = i * 2048 + tid * 4;
                *(float4*)(xtile + f) = *(const float4*)(xsrc + f);
            }
        }
        __syncthreads();   // A: xtile ready; also orders garr2/part reuse

        // ---- 2. prefetch tagged h(t-1) words (RT hides under x-proj) ----
        // Proven timing: AFTER x-stage + barrier A. Do not move earlier.
        unsigned long long v[WPT];
        const unsigned int tag = (unsigned int)t;   // producers wrote (t-1)+1
        const unsigned long long* rb =
            ring + ((size_t)((t - 1) & 3) * BG + bg) * HWORDS;
        if (t > 0) {
            #pragma unroll
            for (int w = 0; w < WPT; ++w)
                v[w] = __hip_atomic_load(rb + w * NTHR + tid,
                                         __ATOMIC_RELAXED,
                                         __HIP_MEMORY_SCOPE_SYSTEM);
        }

        // ---- 3. x projection (16 b128 reads, 256 FMAs) ----
        float acc[4][BPB];
        #pragma unroll
        for (int r = 0; r < 4; ++r)
            #pragma unroll
            for (int b = 0; b < BPB; ++b) acc[r][b] = 0.0f;

        #pragma unroll
        for (int hf = 0; hf < 2; ++hf) {
            #pragma unroll
            for (int b = 0; b < BPB; ++b) {
                const float4 vx = *(const float4*)(xtile + b * IDIM + ks * 8 + hf * 4);
                #pragma unroll
                for (int r = 0; r < 4; ++r) {
                    acc[r][b] = fmaf(wih[r][hf].x, vx.x, acc[r][b]);
                    acc[r][b] = fmaf(wih[r][hf].y, vx.y, acc[r][b]);
                    acc[r][b] = fmaf(wih[r][hf].z, vx.z, acc[r][b]);
                    acc[r][b] = fmaf(wih[r][hf].w, vx.w, acc[r][b]);
                }
            }
        }

        // ---- 4. validate tags; reload stragglers; write h into htile ----
        if (t > 0) {
            for (int sweep = 0; sweep < 30000; ++sweep) {
                bool ok = true;
                #pragma unroll
                for (int w = 0; w < WPT; ++w) {
                    if ((unsigned int)v[w] != tag) {
                        v[w] = __hip_atomic_load(rb + w * NTHR + tid,
                                                 __ATOMIC_RELAXED,
                                                 __HIP_MEMORY_SCOPE_SYSTEM);
                        ok = false;
                    }
                }
                if (ok) break;                     // bail path -> visible error
                __builtin_amdgcn_s_sleep(1);
            }
            #pragma unroll
            for (int w = 0; w < WPT; ++w)
                htile[w * NTHR + tid] =
                    __uint_as_float((unsigned int)(v[w] >> 32));
        } else {
            const float* hsrc = h0 + (size_t)bg * BPB * HDIM;
            #pragma unroll
            for (int i = 0; i < 2; ++i) {
                const int f = i * 2048 + tid * 4;
                *(float4*)(htile + f) = *(const float4*)(hsrc + f);
            }
        }
        __syncthreads();   // D: htile ready

        // ---- 5. h projection (16 b128 reads, 256 FMAs) ----
        #pragma unroll
        for (int hf = 0; hf < 2; ++hf) {
            #pragma unroll
            for (int b = 0; b < BPB; ++b) {
                const float4 vh = *(const float4*)(htile + b * HDIM + ks * 8 + hf * 4);
                #pragma unroll
                for (int r = 0; r < 4; ++r) {
                    acc[r][b] = fmaf(whh[r][hf].x, vh.x, acc[r][b]);
                    acc[r][b] = fmaf(whh[r][hf].y, vh.y, acc[r][b]);
                    acc[r][b] = fmaf(whh[r][hf].z, vh.z, acc[r][b]);
                    acc[r][b] = fmaf(whh[r][hf].w, vh.w, acc[r][b]);
                }
            }
        }

        // ---- 6. spill partials (2-way free conflicts) ----
        #pragma unroll
        for (int r = 0; r < 4; ++r) {
            const int lr = rq * 4 + r;
            #pragma unroll
            for (int b = 0; b < BPB; ++b)
                part[lr * PSTRIDE + b * 64 + ks] = acc[r][b];
        }
        __syncthreads();   // E

        // ---- 7. reduce 64 k-cols: all 512 threads, half-column each ----
        {
            const int lr   = tid & 31;
            const int bh   = tid >> 5;        // 0..15
            const int b    = bh & 7;
            const int half = bh >> 3;         // 0 or 1
            const float* p = part + lr * PSTRIDE + b * 64 + half * 32;
            float s0 = 0.f, s1 = 0.f, s2 = 0.f, s3 = 0.f;
            #pragma unroll
            for (int k2 = 0; k2 < 32; k2 += 4) {
                s0 += p[k2]; s1 += p[k2 + 1]; s2 += p[k2 + 2]; s3 += p[k2 + 3];
            }
            float s = (s0 + s1) + (s2 + s3);
            if (half == 0) s += biasl[lr];
            garr2[half * (RPB * 9) + lr * 9 + b] = s;
        }
        __syncthreads();   // F

        // ---- 8. activations, state update, publish (wave 0, 1 cell) ----
        if (tid < 64) {
            const int i0 = (0 * 8 + j1) * 9 + ab;
            const int i1 = (1 * 8 + j1) * 9 + ab;
            const int i2 = (2 * 8 + j1) * 9 + ab;
            const int i3 = (3 * 8 + j1) * 9 + ab;
            const float ig = sigmoid_f(garr2[i0] + garr2[RPB * 9 + i0]);
            const float fg = sigmoid_f(garr2[i1] + garr2[RPB * 9 + i1]);
            const float gg = tanh_f  (garr2[i2] + garr2[RPB * 9 + i2]);
            const float og = sigmoid_f(garr2[i3] + garr2[RPB * 9 + i3]);
            cst = fmaf(fg, cst, ig * gg);
            hl  = og * tanh_f(cst);

            // tagged ring publish FIRST (earliest visibility on chain)
            unsigned long long* rw = ring
                + ((size_t)(t & 3) * BG + bg) * HWORDS
                + ab * HDIM + jg * JPB + j1;
            __hip_atomic_store(rw,
                (((unsigned long long)__float_as_uint(hl)) << 32)
                    | (unsigned long long)(t + 1),
                __ATOMIC_RELAXED, __HIP_MEMORY_SCOPE_SYSTEM);

            // output store (plain; nobody reads out[] during the run)
            out[((size_t)t * BATCH + bg * BPB + ab) * HDIM + jg * JPB + j1] = hl;
        }
        // no barrier here: A/D/E/F already separate all cross-step hazards
    }

    // ---- final states h_f, c_f ----
    if (tid < 64) {
        const size_t base = (size_t)T_STEPS * BATCH * HDIM;
        const size_t off  = (size_t)(bg * BPB + ab) * HDIM + jg * JPB + j1;
        out[base + off] = hl;
        out[base + (size_t)BATCH * HDIM + off] = cst;
    }
}

extern "C" void kernel_launch(void* const* d_in, const int* in_sizes, int n_in,
                              void* d_out, int out_size, void* d_ws, size_t ws_size,
                              hipStream_t stream) {
    const float* x   = (const float*)d_in[0];
    const float* h0  = (const float*)d_in[1];
    const float* c0  = (const float*)d_in[2];
    const float* Wih = (const float*)d_in[3];
    const float* Whh = (const float*)d_in[4];
    const float* bih = (const float*)d_in[5];
    const float* bhh = (const float*)d_in[6];
    float* out = (float*)d_out;
    unsigned long long* ring = (unsigned long long*)d_ws;  // 512 KB; 0xAA poison
                                                           // != any tag -> no init
    lstm_persistent<<<dim3(NBLK), dim3(NTHR), 0, stream>>>(
        x, h0, c0, Wih, Whh, bih, bhh, out, ring);
}